// Round 1
// baseline (323.131 us; speedup 1.0000x reference)
//
#include <hip/hip_runtime.h>

#define BDIM 512
#define PACK_BDIM 256

typedef __attribute__((ext_vector_type(8))) short bf16x8;
typedef __attribute__((ext_vector_type(4))) float f32x4;
typedef __attribute__((ext_vector_type(4))) unsigned int u32x4;

__device__ __forceinline__ unsigned short f2b(float x) {
    unsigned u = __float_as_uint(x);
    return (unsigned short)((u + 0x7fffu + ((u >> 16) & 1u)) >> 16);
}
__device__ __forceinline__ float b2f(unsigned short b) {
    return __uint_as_float(((unsigned)b) << 16);
}

// Pack 9 fp32 128x128 weights into bf16 hi/lo, fragment-direct layout:
// per gemm g: chunk q = (c*8+f)*2+s (c=K-chunk 0..3, f=N-frag 0..7, s=0 hi,1 lo),
// byte addr = g*65536 + q*1024 + lane*16, holding 8 bf16 for
// k = c*32 + (lane>>4)*8 + i, n = f*16 + (lane&15).
__global__ __launch_bounds__(PACK_BDIM) void pack_weights(
    const float* __restrict__ w0, const float* __restrict__ w1,
    const float* __restrict__ w2, const float* __restrict__ w3,
    const float* __restrict__ w4, const float* __restrict__ w5,
    const float* __restrict__ w6, const float* __restrict__ w7,
    const float* __restrict__ w8, unsigned short* __restrict__ wp)
{
    __shared__ float wsm[16384];
    const float* W;
    switch (blockIdx.x) {
        case 0: W = w0; break; case 1: W = w1; break; case 2: W = w2; break;
        case 3: W = w3; break; case 4: W = w4; break; case 5: W = w5; break;
        case 6: W = w6; break; case 7: W = w7; break; default: W = w8; break;
    }
    const int tid = threadIdx.x;
    for (int i = tid; i < 16384; i += PACK_BDIM) wsm[i] = W[i];
    __syncthreads();
    unsigned short* dst = wp + (size_t)blockIdx.x * 32768;
    for (int item = tid; item < 4096; item += PACK_BDIM) {
        const int lane = item & 63, q = item >> 6;
        const int s = q & 1, fc = q >> 1, f = fc & 7, c = fc >> 3;
        const int k0 = c * 32 + (lane >> 4) * 8;
        const int n  = f * 16 + (lane & 15);
        unsigned v2[4];
        for (int i2 = 0; i2 < 4; i2++) {
            unsigned short lohi[2];
            for (int t = 0; t < 2; t++) {
                float x = wsm[(k0 + i2 * 2 + t) * 128 + n];
                unsigned short hb = f2b(x);
                if (s) { hb = f2b(x - b2f(hb)); }
                lohi[t] = hb;
            }
            v2[i2] = (unsigned)lohi[0] | ((unsigned)lohi[1] << 16);
        }
        u32x4 vv; vv[0] = v2[0]; vv[1] = v2[1]; vv[2] = v2[2]; vv[3] = v2[3];
        *(u32x4*)(dst + (size_t)q * 512 + lane * 8) = vv;
    }
}

// Fused dual-input GRU cell. grid = B/128 blocks, 512 threads (8 waves x 16 rows).
// gemm ids: 0 ir, 1 iz, 2 in_, 3 sr, 4 sz, 5 sn, 6 hr, 7 hz, 8 hn.
__global__ __launch_bounds__(BDIM) void gru_fused(
    const float* __restrict__ inp, const float* __restrict__ seqp,
    const float* __restrict__ hid, const unsigned short* __restrict__ wp,
    const float* __restrict__ b_ir, const float* __restrict__ b_iz,
    const float* __restrict__ b_in, const float* __restrict__ b_sr,
    const float* __restrict__ b_sz, const float* __restrict__ b_sn,
    const float* __restrict__ b_hr, const float* __restrict__ b_hz,
    const float* __restrict__ b_hn, float* __restrict__ outp)
{
    __shared__ unsigned short wbuf[32768]; // 64 KiB: current gemm's hi/lo weights
    __shared__ float rbuf[16384];          // 64 KiB: r gate, XOR-swizzled [row][col^((row&7)<<3)]
    const int tid  = threadIdx.x;
    const int lane = tid & 63;
    const int wid  = tid >> 6;
    const int agrp = lane >> 4;   // k-group for A/B frags
    const int a16  = lane & 15;   // M for A-frag, N for B-frag, col for C-frag
    const size_t row0 = (size_t)blockIdx.x * 128;

    const size_t arow = row0 + (size_t)(wid * 16 + a16); // A-layout absolute row
    const float* pAin  = inp  + arow * 128;
    const float* pAseq = seqp + arow * 128;
    const float* pAhid = hid  + arow * 128;
    const int locrow_a = wid * 16 + a16;
    const int rsw = (locrow_a & 7) << 3;

    f32x4 hx[8], t[8], s1[8];
    const f32x4 zv = {0.f, 0.f, 0.f, 0.f};

    auto stage = [&](int g) {
        const u32x4* src = (const u32x4*)wp + (size_t)g * 4096;
        u32x4* dst = (u32x4*)wbuf;
        #pragma unroll
        for (int j = 0; j < 8; j++) dst[j * BDIM + tid] = src[j * BDIM + tid];
    };

    // acc += A @ Wg  (A fp32 from global, split into bf16 hi/lo; W pre-split in LDS)
    auto mm = [&](f32x4* acc, const float* pA, bool withR, bool init) {
        if (init) {
            #pragma unroll
            for (int f = 0; f < 8; f++) acc[f] = zv;
        }
        #pragma unroll
        for (int c = 0; c < 4; c++) {
            const float* p = pA + c * 32 + agrp * 8;
            f32x4 x0 = *(const f32x4*)(p);
            f32x4 x1 = *(const f32x4*)(p + 4);
            float xs[8];
            #pragma unroll
            for (int i = 0; i < 4; i++) { xs[i] = x0[i]; xs[4 + i] = x1[i]; }
            if (withR) {
                const int rk = (c * 32 + agrp * 8) ^ rsw;
                const f32x4 r0 = *(const f32x4*)(&rbuf[locrow_a * 128 + rk]);
                const f32x4 r1 = *(const f32x4*)(&rbuf[locrow_a * 128 + rk + 4]);
                #pragma unroll
                for (int i = 0; i < 4; i++) { xs[i] *= r0[i]; xs[4 + i] *= r1[i]; }
            }
            bf16x8 ah, al;
            #pragma unroll
            for (int i = 0; i < 8; i++) {
                float x = xs[i];
                unsigned short hb = f2b(x);
                ah[i] = (short)hb;
                al[i] = (short)f2b(x - b2f(hb));
            }
            #pragma unroll
            for (int f = 0; f < 8; f++) {
                const bf16x8 wh = *(const bf16x8*)(&wbuf[(size_t)((c * 8 + f) * 2 + 0) * 512 + lane * 8]);
                const bf16x8 wl = *(const bf16x8*)(&wbuf[(size_t)((c * 8 + f) * 2 + 1) * 512 + lane * 8]);
                acc[f] = __builtin_amdgcn_mfma_f32_16x16x32_bf16(ah, wh, acc[f], 0, 0, 0);
                acc[f] = __builtin_amdgcn_mfma_f32_16x16x32_bf16(al, wh, acc[f], 0, 0, 0);
                acc[f] = __builtin_amdgcn_mfma_f32_16x16x32_bf16(ah, wl, acc[f], 0, 0, 0);
            }
        }
    };

    auto addb = [&](f32x4* acc, const float* b) {
        #pragma unroll
        for (int f = 0; f < 8; f++) {
            float bv = b[f * 16 + a16];
            #pragma unroll
            for (int j = 0; j < 4; j++) acc[f][j] += bv;
        }
    };

    auto sigm = [](float x) { return 1.f / (1.f + __expf(-x)); };
    auto tanh_ = [](float x) {
        x = fminf(18.f, fmaxf(-18.f, x));
        float e = __expf(2.f * x);
        return (e - 1.f) / (e + 1.f);
    };

    // ---------- r gate ----------
    stage(6); __syncthreads();
    mm(hx, pAhid, false, true); addb(hx, b_hr);          // hr (shared)
    __syncthreads(); stage(0); __syncthreads();
    mm(t, pAin, false, true);  addb(t, b_ir);
    #pragma unroll
    for (int f = 0; f < 8; f++)
        #pragma unroll
        for (int j = 0; j < 4; j++) s1[f][j] = sigm(t[f][j] + hx[f][j]);  // r_input
    __syncthreads(); stage(3); __syncthreads();
    mm(t, pAseq, false, true); addb(t, b_sr);
    #pragma unroll
    for (int f = 0; f < 8; f++)
        #pragma unroll
        for (int j = 0; j < 4; j++) {
            float r = 0.5f * (s1[f][j] + sigm(t[f][j] + hx[f][j]));
            int row = wid * 16 + agrp * 4 + j;               // C-layout local row
            int col = f * 16 + a16;
            rbuf[row * 128 + (col ^ ((row & 7) << 3))] = r;  // same-wave consumer only
        }

    // ---------- z gate ----------
    __syncthreads(); stage(7); __syncthreads();
    mm(hx, pAhid, false, true); addb(hx, b_hz);          // hz (shared)
    __syncthreads(); stage(1); __syncthreads();
    mm(t, pAin, false, true);  addb(t, b_iz);
    #pragma unroll
    for (int f = 0; f < 8; f++)
        #pragma unroll
        for (int j = 0; j < 4; j++) s1[f][j] = sigm(t[f][j] + hx[f][j]);  // z_input
    __syncthreads(); stage(4); __syncthreads();
    mm(t, pAseq, false, true); addb(t, b_sz);
    #pragma unroll
    for (int f = 0; f < 8; f++)
        #pragma unroll
        for (int j = 0; j < 4; j++)
            s1[f][j] = 0.5f * (s1[f][j] + sigm(t[f][j] + hx[f][j]));      // s1 = z (persists)

    // ---------- n ----------
    __syncthreads(); stage(2); __syncthreads();
    mm(t, pAin, false, true);  addb(t, b_in);
    __syncthreads(); stage(5); __syncthreads();
    mm(t, pAseq, false, false); addb(t, b_sn);
    __syncthreads(); stage(8); __syncthreads();
    mm(t, pAhid, true, false); addb(t, b_hn);            // (r*hidden) @ W_hn

    // ---------- blend & store ----------
    #pragma unroll
    for (int f = 0; f < 8; f++)
        #pragma unroll
        for (int j = 0; j < 4; j++) {
            int row = wid * 16 + agrp * 4 + j;
            size_t gidx = (row0 + row) * 128 + f * 16 + a16;
            float h  = hid[gidx];
            float nn = tanh_(t[f][j]);
            float zz = s1[f][j];
            outp[gidx] = (1.f - zz) * nn + zz * h;
        }
}

extern "C" void kernel_launch(void* const* d_in, const int* in_sizes, int n_in,
                              void* d_out, int out_size, void* d_ws, size_t ws_size,
                              hipStream_t stream)
{
    (void)in_sizes; (void)n_in; (void)out_size; (void)ws_size;
    const float* inp  = (const float*)d_in[0];
    const float* seqp = (const float*)d_in[1];
    const float* hid  = (const float*)d_in[2];
    const float* W[9]; const float* Bv[9];
    for (int i = 0; i < 9; i++) {
        W[i]  = (const float*)d_in[3 + 2 * i];
        Bv[i] = (const float*)d_in[4 + 2 * i];
    }
    unsigned short* wp = (unsigned short*)d_ws; // needs 589,824 B

    pack_weights<<<9, PACK_BDIM, 0, stream>>>(W[0], W[1], W[2], W[3], W[4],
                                              W[5], W[6], W[7], W[8], wp);
    gru_fused<<<1024, BDIM, 0, stream>>>(inp, seqp, hid, wp,
                                         Bv[0], Bv[1], Bv[2], Bv[3], Bv[4],
                                         Bv[5], Bv[6], Bv[7], Bv[8],
                                         (float*)d_out);
}